// Round 3
// baseline (2892.444 us; speedup 1.0000x reference)
//
#include <hip/hip_runtime.h>

// ---------------------------------------------------------------------------
// SparseKT forward, MI355X gfx950. I/O dtype: fp32 (per reference).
// Numerics: fp32 tensors decomposed into hi/lo bf16 pairs (pseudo-fp32,
// rel err ~2^-17). GEMMs are split-3: C = Ah*Bh + Ah*Bl + Al*Bh (3 MFMAs).
// Softmax / exact top-5 / LayerNorm in fp32. Residual stream: hi/lo pairs.
// Workspace ~151 MB (round-1's 325 MB overflowed => abort; keep lean).
// ---------------------------------------------------------------------------

#define L_   2
#define B_   32
#define S_   512
#define D_   512
#define H_   8
#define DH_  64
#define DFF_ 2048
#define BS_  (B_*S_)      // 16384

typedef __bf16 bfx8 __attribute__((ext_vector_type(8)));
typedef float floatx4 __attribute__((ext_vector_type(4)));

__device__ __forceinline__ floatx4 mfma_bf16(bfx8 a, bfx8 b, floatx4 c) {
  return __builtin_amdgcn_mfma_f32_16x16x32_bf16(a, b, c, 0, 0, 0);
}

__device__ __forceinline__ float wave_sum(float v) {
  #pragma unroll
  for (int d = 32; d > 0; d >>= 1) v += __shfl_xor(v, d);
  return v;
}
__device__ __forceinline__ float wave_max(float v) {
  #pragma unroll
  for (int d = 32; d > 0; d >>= 1) v = fmaxf(v, __shfl_xor(v, d));
  return v;
}

// ---------------------------------------------------------------------------
// init: x = question_emb + pos (fp32) -> bf16 hi/lo pair
// ---------------------------------------------------------------------------
__global__ void init_x_kernel(const float* __restrict__ qe, const float* __restrict__ pos,
                              __bf16* __restrict__ xh, __bf16* __restrict__ xl)
{
  size_t i = ((size_t)blockIdx.x * 256 + threadIdx.x) * 8;
  float4 a0 = *(const float4*)(qe + i);
  float4 a1 = *(const float4*)(qe + i + 4);
  size_t pi = i & (size_t)(S_*D_ - 1);
  float4 p0 = *(const float4*)(pos + pi);
  float4 p1 = *(const float4*)(pos + pi + 4);
  float v[8] = {a0.x+p0.x, a0.y+p0.y, a0.z+p0.z, a0.w+p0.w,
                a1.x+p1.x, a1.y+p1.y, a1.z+p1.z, a1.w+p1.w};
  bfx8 hv8, lv8;
  #pragma unroll
  for (int j = 0; j < 8; ++j) {
    __bf16 hv = (__bf16)v[j];
    hv8[j] = hv;
    lv8[j] = (__bf16)(v[j] - (float)hv);
  }
  *(bfx8*)(xh + i) = hv8;
  *(bfx8*)(xl + i) = lv8;
}

// ---------------------------------------------------------------------------
// weight transpose + hi/lo split:  W[K][N] fp32  ->  T{h,l}[N][K] bf16
// ---------------------------------------------------------------------------
__global__ void transpose_split_kernel(const float* __restrict__ Wsrc,
                                       __bf16* __restrict__ Th, __bf16* __restrict__ Tl,
                                       int K, int N)
{
  __shared__ float tile[32][33];
  int n0 = blockIdx.x * 32, k0 = blockIdx.y * 32;
  int tx = threadIdx.x & 31, ty8 = threadIdx.x >> 5;  // 0..7
  #pragma unroll
  for (int j = 0; j < 4; ++j) {
    int k = ty8 + j*8;
    tile[k][tx] = Wsrc[(size_t)(k0 + k) * N + n0 + tx];
  }
  __syncthreads();
  #pragma unroll
  for (int j = 0; j < 4; ++j) {
    int n = ty8 + j*8;
    float vv = tile[tx][n];           // = W[k0+tx][n0+n]
    size_t dst = (size_t)(n0 + n) * K + k0 + tx;
    __bf16 hv = (__bf16)vv;
    Th[dst] = hv;
    Tl[dst] = (__bf16)(vv - (float)hv);
  }
}

// ---------------------------------------------------------------------------
// split-3 GEMM: C[M,N] = A[M,K] @ Bt[N,K]^T + bias; output bf16 hi/lo pair.
// flags: 1 = relu, 4 = stage A from fp32 (Afa[m] + Afp[m mod S]) on the fly
//            (fused y = interaction_emb + pos for the V projection)
// 128x128x32 tile, 4 waves, each wave a 64x64 quadrant (16 MFMA tiles).
// ---------------------------------------------------------------------------
__global__ __launch_bounds__(256, 2)
void gemm_split3_kernel(const __bf16* __restrict__ Ah, const __bf16* __restrict__ Al,
                        const float* __restrict__ Afa, const float* __restrict__ Afp,
                        const __bf16* __restrict__ Bth, const __bf16* __restrict__ Btl,
                        const float* __restrict__ bias,
                        __bf16* __restrict__ Ch, __bf16* __restrict__ Cl,
                        int M, int N, int K, int flags)
{
  constexpr int LDT = 40;   // 32 + 8 pad (bf16 elems), keeps 16B alignment
  __shared__ __bf16 sAh[128*LDT], sAl[128*LDT], sBh[128*LDT], sBl[128*LDT];
  const int t = threadIdx.x;
  const int w = t >> 6, lane = t & 63;
  const int q4 = lane >> 4, r16 = lane & 15;
  const int m0 = blockIdx.y * 128, n0 = blockIdx.x * 128;
  const int wm = (w >> 1) * 64, wn = (w & 1) * 64;

  floatx4 acc[4][4];
  #pragma unroll
  for (int i = 0; i < 4; ++i)
    #pragma unroll
    for (int j = 0; j < 4; ++j)
      acc[i][j] = (floatx4){0.f, 0.f, 0.f, 0.f};

  const int srow = t >> 2;          // 0..63
  const int scol = (t & 3) * 8;     // 0,8,16,24

  for (int k0 = 0; k0 < K; k0 += 32) {
    __syncthreads();
    #pragma unroll
    for (int c = 0; c < 2; ++c) {
      int row = srow + c * 64;
      bfx8 hv8, lv8;
      if (flags & 4) {
        size_t ga = (size_t)(m0 + row) * K + k0 + scol;
        size_t gp = (size_t)((m0 + row) & (S_ - 1)) * K + k0 + scol;
        float4 e0 = *(const float4*)&Afa[ga];
        float4 e1 = *(const float4*)&Afa[ga + 4];
        float4 p0 = *(const float4*)&Afp[gp];
        float4 p1 = *(const float4*)&Afp[gp + 4];
        float sv[8] = {e0.x+p0.x, e0.y+p0.y, e0.z+p0.z, e0.w+p0.w,
                       e1.x+p1.x, e1.y+p1.y, e1.z+p1.z, e1.w+p1.w};
        #pragma unroll
        for (int j = 0; j < 8; ++j) {
          __bf16 hv = (__bf16)sv[j];
          hv8[j] = hv;
          lv8[j] = (__bf16)(sv[j] - (float)hv);
        }
      } else {
        size_t ga = (size_t)(m0 + row) * K + k0 + scol;
        hv8 = *(const bfx8*)&Ah[ga];
        lv8 = *(const bfx8*)&Al[ga];
      }
      *(bfx8*)&sAh[row*LDT + scol] = hv8;
      *(bfx8*)&sAl[row*LDT + scol] = lv8;
      size_t gb = (size_t)(n0 + row) * K + k0 + scol;
      *(bfx8*)&sBh[row*LDT + scol] = *(const bfx8*)&Bth[gb];
      *(bfx8*)&sBl[row*LDT + scol] = *(const bfx8*)&Btl[gb];
    }
    __syncthreads();
    bfx8 af[4][2], bfr[4][2];
    #pragma unroll
    for (int i = 0; i < 4; ++i) {
      int ar = wm + i*16 + r16;
      af[i][0] = *(const bfx8*)&sAh[ar*LDT + q4*8];
      af[i][1] = *(const bfx8*)&sAl[ar*LDT + q4*8];
      int br = wn + i*16 + r16;
      bfr[i][0] = *(const bfx8*)&sBh[br*LDT + q4*8];
      bfr[i][1] = *(const bfx8*)&sBl[br*LDT + q4*8];
    }
    #pragma unroll
    for (int i = 0; i < 4; ++i)
      #pragma unroll
      for (int j = 0; j < 4; ++j) {
        acc[i][j] = mfma_bf16(af[i][0], bfr[j][0], acc[i][j]);
        acc[i][j] = mfma_bf16(af[i][0], bfr[j][1], acc[i][j]);
        acc[i][j] = mfma_bf16(af[i][1], bfr[j][0], acc[i][j]);
      }
  }

  // epilogue (C/D layout: col = lane&15, row = (lane>>4)*4 + reg  [m89-verified])
  #pragma unroll
  for (int i = 0; i < 4; ++i)
    #pragma unroll
    for (int j = 0; j < 4; ++j) {
      int gn = n0 + wn + j*16 + r16;
      float bb = bias[gn];
      #pragma unroll
      for (int r = 0; r < 4; ++r) {
        int gm = m0 + wm + i*16 + q4*4 + r;
        float val = acc[i][j][r] + bb;
        if (flags & 1) val = fmaxf(val, 0.f);
        size_t co = (size_t)gm * N + gn;
        __bf16 hv = (__bf16)val;
        Ch[co] = hv;
        Cl[co] = (__bf16)(val - (float)hv);
      }
    }
}

// ---------------------------------------------------------------------------
// attention: one block per (qt, h, b); 16 queries/block.
// scores (hi/lo MFMA, K=Q buffer: kq_same) -> strictly-causal mask ->
// softmax -> zero row 0 -> exact top-5 threshold + re-softmax (rows > 5) ->
// P @ V (hi/lo MFMA), O written as bf16 hi/lo.
// ---------------------------------------------------------------------------
__global__ __launch_bounds__(256, 1)
void attn_kernel(const __bf16* __restrict__ qh, const __bf16* __restrict__ ql,
                 const __bf16* __restrict__ vh, const __bf16* __restrict__ vl,
                 __bf16* __restrict__ oh, __bf16* __restrict__ ol)
{
  constexpr int LSS = 516;                       // fp32 row stride (pad 4)
  __shared__ float  Ssc[16*LSS];                 // 33 KB score/prob rows
  __shared__ __bf16 KVh[64*72];                  // K tile, reused for V^T tile
  __shared__ __bf16 KVl[64*72];
  const int qt = blockIdx.x, hd = blockIdx.y, b = blockIdx.z;
  const int t = threadIdx.x, w = t >> 6, lane = t & 63;
  const int q4 = lane >> 4, r16 = lane & 15;
  const int nkt = (qt >> 2) + 1;                 // 64-key tiles needed (causal)

  // Q fragments (A operand): rows qt*16+[0,16), cols hd*64+[0,64)
  bfx8 qf[2][2];
  {
    size_t base = ((size_t)(b*S_ + qt*16 + r16)) * D_ + hd*64;
    #pragma unroll
    for (int ks = 0; ks < 2; ++ks) {
      qf[ks][0] = *(const bfx8*)&qh[base + ks*32 + q4*8];
      qf[ks][1] = *(const bfx8*)&ql[base + ks*32 + q4*8];
    }
  }

  const int srow8 = t >> 3;        // 0..31
  const int scol8 = (t & 7) * 8;   // 0..56

  // ---- phase 1: scores ----
  for (int kt = 0; kt < nkt; ++kt) {
    __syncthreads();
    #pragma unroll
    for (int c = 0; c < 2; ++c) {     // stage K tile [64 keys][64 dh]
      int row = srow8 + c*32;
      size_t src = ((size_t)(b*S_ + kt*64 + row)) * D_ + hd*64 + scol8;
      *(bfx8*)&KVh[row*72 + scol8] = *(const bfx8*)&qh[src];
      *(bfx8*)&KVl[row*72 + scol8] = *(const bfx8*)&ql[src];
    }
    __syncthreads();
    floatx4 acc = (floatx4){0.f, 0.f, 0.f, 0.f};
    #pragma unroll
    for (int ks = 0; ks < 2; ++ks) {
      bfx8 kbh = *(const bfx8*)&KVh[(w*16 + r16)*72 + ks*32 + q4*8];
      bfx8 kbl = *(const bfx8*)&KVl[(w*16 + r16)*72 + ks*32 + q4*8];
      acc = mfma_bf16(qf[ks][0], kbh, acc);
      acc = mfma_bf16(qf[ks][0], kbl, acc);
      acc = mfma_bf16(qf[ks][1], kbh, acc);
    }
    int gcol = kt*64 + w*16 + r16;
    #pragma unroll
    for (int r = 0; r < 4; ++r) {
      int lrow = q4*4 + r;
      int grow = qt*16 + lrow;
      float sc = acc[r] * 0.125f;          // / sqrt(64)
      if (gcol >= grow) sc = -1e32f;       // strictly causal (tril k=-1), ref value
      Ssc[lrow*LSS + gcol] = sc;
    }
  }
  __syncthreads();

  // ---- phase 2: softmax + exact top-5 re-softmax (wave w owns rows w*4..w*4+3) ----
  for (int rr = 0; rr < 4; ++rr) {
    int lrow = w*4 + rr;
    int grow = qt*16 + lrow;
    float p[8];
    float mx = -3.0e38f;
    for (int j = 0; j < nkt; ++j) {
      p[j] = Ssc[lrow*LSS + j*64 + lane];
      mx = fmaxf(mx, p[j]);
    }
    mx = wave_max(mx);
    float s = 0.f;
    for (int j = 0; j < nkt; ++j) { p[j] = __expf(p[j] - mx); s += p[j]; }
    s = wave_sum(s);
    for (int j = 0; j < nkt; ++j) p[j] = p[j] / s;
    if (grow == 0) {                                   // zero_pad row
      for (int j = 0; j < nkt; ++j) Ssc[lrow*LSS + j*64 + lane] = 0.f;
      continue;
    }
    if (grow <= 5) {                                   // row <= K_INDEX: plain softmax
      for (int j = 0; j < nkt; ++j) Ssc[lrow*LSS + j*64 + lane] = p[j];
      continue;
    }
    // exact 5th order statistic (with duplicates, matching lax.top_k)
    unsigned rm = 0;
    float pmax = 0.f, thr = 0.f;
    for (int it = 0; it < 5; ++it) {
      float loc = -1.f; int locj = 0;
      for (int j = 0; j < nkt; ++j)
        if (!((rm >> j) & 1u) && p[j] > loc) { loc = p[j]; locj = j; }
      float wmx = wave_max(loc);
      if (it == 0) pmax = wmx;
      thr = wmx;
      unsigned long long ball = __ballot(loc == wmx);
      int first = (int)__builtin_ctzll(ball);          // remove exactly one instance
      if (lane == first) rm |= 1u << locj;
    }
    float s2 = 0.f;
    for (int j = 0; j < nkt; ++j) {
      float vv = (p[j] - thr >= 0.f) ? __expf(p[j] - pmax) : 0.f;
      p[j] = vv; s2 += vv;
    }
    s2 = wave_sum(s2);
    for (int j = 0; j < nkt; ++j) Ssc[lrow*LSS + j*64 + lane] = p[j] / s2;
  }

  // ---- phase 3: O = P @ V ----
  floatx4 oacc = (floatx4){0.f, 0.f, 0.f, 0.f};
  for (int vt = 0; vt < nkt; ++vt) {
    __syncthreads();
    #pragma unroll
    for (int c = 0; c < 2; ++c) {     // stage V tile transposed: KV[dh][key]
      int key = srow8 + c*32;
      size_t src = ((size_t)(b*S_ + vt*64 + key)) * D_ + hd*64 + scol8;
      bfx8 a = *(const bfx8*)&vh[src];
      bfx8 bb = *(const bfx8*)&vl[src];
      #pragma unroll
      for (int i = 0; i < 8; ++i) {
        KVh[(scol8 + i)*72 + key] = a[i];
        KVl[(scol8 + i)*72 + key] = bb[i];
      }
    }
    __syncthreads();
    #pragma unroll
    for (int ks = 0; ks < 2; ++ks) {
      const float* pr = &Ssc[r16*LSS + vt*64 + ks*32 + q4*8];
      bfx8 ph, pl;
      #pragma unroll
      for (int i = 0; i < 8; ++i) {
        float pv = pr[i];
        __bf16 hv = (__bf16)pv;
        ph[i] = hv;
        pl[i] = (__bf16)(pv - (float)hv);
      }
      bfx8 vbh = *(const bfx8*)&KVh[(w*16 + r16)*72 + ks*32 + q4*8];
      bfx8 vbl = *(const bfx8*)&KVl[(w*16 + r16)*72 + ks*32 + q4*8];
      oacc = mfma_bf16(ph, vbh, oacc);
      oacc = mfma_bf16(ph, vbl, oacc);
      oacc = mfma_bf16(pl, vbh, oacc);
    }
  }
  #pragma unroll
  for (int r = 0; r < 4; ++r) {
    int grow = qt*16 + q4*4 + r;
    size_t off = ((size_t)(b*S_ + grow)) * D_ + hd*64 + w*16 + r16;
    float val = oacc[r];
    __bf16 hv = (__bf16)val;
    oh[off] = hv;
    ol[off] = (__bf16)(val - (float)hv);
  }
}

// ---------------------------------------------------------------------------
// residual + LayerNorm (fp32): x = LN(xh+xl + th+tl); writes bf16 hi/lo pair
// and (if fout) the exact fp32 result. 1 wave/row, 4 rows/block.
// ---------------------------------------------------------------------------
__global__ void resid_ln_kernel(const __bf16* __restrict__ xhin, const __bf16* __restrict__ xlin,
                                const __bf16* __restrict__ thin, const __bf16* __restrict__ tlin,
                                const float* __restrict__ g, const float* __restrict__ bb,
                                __bf16* __restrict__ xh, __bf16* __restrict__ xl,
                                float* __restrict__ fout)
{
  int row = blockIdx.x * 4 + (threadIdx.x >> 6);
  int lane = threadIdx.x & 63;
  size_t base = (size_t)row * D_ + lane * 8;
  bfx8 h8 = *(const bfx8*)(xhin + base);
  bfx8 l8 = *(const bfx8*)(xlin + base);
  bfx8 th8 = *(const bfx8*)(thin + base);
  bfx8 tl8 = *(const bfx8*)(tlin + base);
  float v[8];
  #pragma unroll
  for (int j = 0; j < 8; ++j)
    v[j] = ((float)h8[j] + (float)l8[j]) + ((float)th8[j] + (float)tl8[j]);
  float s = 0.f;
  #pragma unroll
  for (int j = 0; j < 8; ++j) s += v[j];
  s = wave_sum(s);
  float mean = s * (1.0f/512.0f);
  float var = 0.f;
  #pragma unroll
  for (int j = 0; j < 8; ++j) { float d = v[j] - mean; var += d*d; }
  var = wave_sum(var) * (1.0f/512.0f);
  float rs = 1.0f / sqrtf(var + 1e-5f);
  float4 g0 = *(const float4*)(g + lane*8);
  float4 g1 = *(const float4*)(g + lane*8 + 4);
  float4 b0 = *(const float4*)(bb + lane*8);
  float4 b1 = *(const float4*)(bb + lane*8 + 4);
  float gg[8]  = {g0.x,g0.y,g0.z,g0.w,g1.x,g1.y,g1.z,g1.w};
  float bbv[8] = {b0.x,b0.y,b0.z,b0.w,b1.x,b1.y,b1.z,b1.w};
  float o[8];
  #pragma unroll
  for (int j = 0; j < 8; ++j) o[j] = (v[j] - mean) * rs * gg[j] + bbv[j];
  bfx8 hv8, lv8;
  #pragma unroll
  for (int j = 0; j < 8; ++j) {
    __bf16 hv = (__bf16)o[j];
    hv8[j] = hv;
    lv8[j] = (__bf16)(o[j] - (float)hv);
  }
  *(bfx8*)(xh + base) = hv8;
  *(bfx8*)(xl + base) = lv8;
  if (fout) {
    *(float4*)(fout + base)     = make_float4(o[0],o[1],o[2],o[3]);
    *(float4*)(fout + base + 4) = make_float4(o[4],o[5],o[6],o[7]);
  }
}

// ---------------------------------------------------------------------------
extern "C" void kernel_launch(void* const* d_in, const int* in_sizes, int n_in,
                              void* d_out, int out_size, void* d_ws, size_t ws_size,
                              hipStream_t stream)
{
  const float* qe   = (const float*)d_in[0];
  const float* ie   = (const float*)d_in[1];
  const float* pos  = (const float*)d_in[2];
  const float* Wk   = (const float*)d_in[3];
  const float* bk   = (const float*)d_in[4];
  const float* Wv   = (const float*)d_in[5];
  const float* bv   = (const float*)d_in[6];
  const float* Wo   = (const float*)d_in[7];
  const float* bo   = (const float*)d_in[8];
  const float* ln1g = (const float*)d_in[9];
  const float* ln1b = (const float*)d_in[10];
  const float* W1   = (const float*)d_in[11];
  const float* b1   = (const float*)d_in[12];
  const float* W2   = (const float*)d_in[13];
  const float* b2   = (const float*)d_in[14];
  const float* ln2g = (const float*)d_in[15];
  const float* ln2b = (const float*)d_in[16];

  char* wsp = (char*)d_ws;
  size_t off = 0;
  auto alloc = [&](size_t bytes) -> void* {
    void* p = wsp + off;
    off += (bytes + 255) & ~(size_t)255;
    return p;
  };
  const size_t NB = (size_t)BS_ * D_ * sizeof(__bf16);   // 16 MB per bf16 activation
  __bf16* xh  = (__bf16*)alloc(NB);
  __bf16* xl  = (__bf16*)alloc(NB);
  // q region aliases t (attn-out-proj / FFN2 result): q dead once out-proj runs
  char*   qt_ = (char*)  alloc(2*NB);
  __bf16* qhb = (__bf16*)qt_;
  __bf16* qlb = (__bf16*)(qt_ + NB);
  __bf16* thb = (__bf16*)qt_;
  __bf16* tlb = (__bf16*)(qt_ + NB);
  __bf16* vhb = (__bf16*)alloc(NB);
  __bf16* vlb = (__bf16*)alloc(NB);
  // o region aliases FFN hidden (M=4096 chunk: 4096*2048*2 B = NB each)
  char*   oh_ = (char*) alloc(2*NB);
  __bf16* ohb = (__bf16*)oh_;
  __bf16* olb = (__bf16*)(oh_ + NB);
  __bf16* hhb = (__bf16*)oh_;
  __bf16* hlb = (__bf16*)(oh_ + NB);
  const size_t LW = 3*(size_t)D_*D_ + 2*(size_t)D_*DFF_;   // elems / layer
  __bf16* wth = (__bf16*)alloc(2*LW*sizeof(__bf16));
  __bf16* wtl = (__bf16*)alloc(2*LW*sizeof(__bf16));
  float*  xout = (float*)d_out;
  // total ws usage ~151 MB

  const size_t OK = 0, OV = (size_t)D_*D_, OO = 2*(size_t)D_*D_;
  const size_t O1 = 3*(size_t)D_*D_, O2 = 3*(size_t)D_*D_ + (size_t)D_*DFF_;

  // weight transposes + splits (recomputed each call; graph-capture safe)
  for (int l = 0; l < L_; ++l) {
    size_t base = (size_t)l * LW;
    transpose_split_kernel<<<dim3(16,16), 256, 0, stream>>>(Wk + (size_t)l*D_*D_,   wth+base+OK, wtl+base+OK, D_,  D_);
    transpose_split_kernel<<<dim3(16,16), 256, 0, stream>>>(Wv + (size_t)l*D_*D_,   wth+base+OV, wtl+base+OV, D_,  D_);
    transpose_split_kernel<<<dim3(16,16), 256, 0, stream>>>(Wo + (size_t)l*D_*D_,   wth+base+OO, wtl+base+OO, D_,  D_);
    transpose_split_kernel<<<dim3(64,16), 256, 0, stream>>>(W1 + (size_t)l*D_*DFF_, wth+base+O1, wtl+base+O1, D_,  DFF_);
    transpose_split_kernel<<<dim3(16,64), 256, 0, stream>>>(W2 + (size_t)l*DFF_*D_, wth+base+O2, wtl+base+O2, DFF_, D_);
  }

  init_x_kernel<<<4096, 256, 0, stream>>>(qe, pos, xh, xl);

  for (int l = 0; l < L_; ++l) {
    size_t base = (size_t)l * LW;
    // q = k = x @ Wk + bk (kq_same), bf16 hi/lo out
    gemm_split3_kernel<<<dim3(4,128), 256, 0, stream>>>(xh, xl, nullptr, nullptr,
        wth+base+OK, wtl+base+OK, bk + (size_t)l*D_, qhb, qlb, BS_, D_, D_, 0);
    // v = (ie + pos) @ Wv + bv  (fused y staging from fp32)
    gemm_split3_kernel<<<dim3(4,128), 256, 0, stream>>>(nullptr, nullptr, ie, pos,
        wth+base+OV, wtl+base+OV, bv + (size_t)l*D_, vhb, vlb, BS_, D_, D_, 4);
    // sparse attention
    attn_kernel<<<dim3(S_/16, H_, B_), 256, 0, stream>>>(qhb, qlb, vhb, vlb, ohb, olb);
    // out-proj -> t (hi/lo; overwrites q region, q is dead)
    gemm_split3_kernel<<<dim3(4,128), 256, 0, stream>>>(ohb, olb, nullptr, nullptr,
        wth+base+OO, wtl+base+OO, bo + (size_t)l*D_, thb, tlb, BS_, D_, D_, 0);
    // x = LN1(x + t)
    resid_ln_kernel<<<BS_/4, 256, 0, stream>>>(xh, xl, thb, tlb,
        ln1g + (size_t)l*D_, ln1b + (size_t)l*D_, xh, xl, nullptr);
    // FFN in four M=4096 chunks (hidden aliases o region, out -> t region)
    for (int ch = 0; ch < 4; ++ch) {
      size_t ao = (size_t)ch*4096*D_;
      gemm_split3_kernel<<<dim3(16,32), 256, 0, stream>>>(xh + ao, xl + ao, nullptr, nullptr,
          wth+base+O1, wtl+base+O1, b1 + (size_t)l*DFF_, hhb, hlb, 4096, DFF_, D_, 1);
      gemm_split3_kernel<<<dim3(4,32), 256, 0, stream>>>(hhb, hlb, nullptr, nullptr,
          wth+base+O2, wtl+base+O2, b2 + (size_t)l*D_, thb + ao, tlb + ao, 4096, D_, DFF_, 0);
    }
    // x = LN2(x + t); final layer writes fp32 straight to d_out
    resid_ln_kernel<<<BS_/4, 256, 0, stream>>>(xh, xl, thb, tlb,
        ln2g + (size_t)l*D_, ln2b + (size_t)l*D_, xh, xl,
        (l == L_-1) ? xout : nullptr);
  }
}

// Round 4
// 2059.771 us; speedup vs baseline: 1.4043x; 1.4043x over previous
//
#include <hip/hip_runtime.h>

// ---------------------------------------------------------------------------
// SparseKT forward, MI355X gfx950. I/O dtype: fp32 (per reference).
// Numerics: fp32 tensors decomposed into hi/lo bf16 pairs (pseudo-fp32,
// rel err ~2^-17). GEMMs are split-3: C = Ah*Bh + Ah*Bl + Al*Bh (3 MFMAs).
// Softmax / exact top-5 / LayerNorm in fp32. Residual stream: hi/lo pairs.
// R3->R4: attn phase-2 loops statically unrolled (p[8] was scratch-spilled:
// VGPR=68, FETCH 246MB), phase-3 uses swapped-operand MFMA (O^T = V^T P^T)
// to kill the 8-way LDS scatter conflicts (7.3e7), heavy q-tiles first.
// ---------------------------------------------------------------------------

#define L_   2
#define B_   32
#define S_   512
#define D_   512
#define H_   8
#define DH_  64
#define DFF_ 2048
#define BS_  (B_*S_)      // 16384

typedef __bf16 bfx8 __attribute__((ext_vector_type(8)));
typedef float floatx4 __attribute__((ext_vector_type(4)));

__device__ __forceinline__ floatx4 mfma_bf16(bfx8 a, bfx8 b, floatx4 c) {
  return __builtin_amdgcn_mfma_f32_16x16x32_bf16(a, b, c, 0, 0, 0);
}

__device__ __forceinline__ float wave_sum(float v) {
  #pragma unroll
  for (int d = 32; d > 0; d >>= 1) v += __shfl_xor(v, d);
  return v;
}
__device__ __forceinline__ float wave_max(float v) {
  #pragma unroll
  for (int d = 32; d > 0; d >>= 1) v = fmaxf(v, __shfl_xor(v, d));
  return v;
}

// ---------------------------------------------------------------------------
// init: x = question_emb + pos (fp32) -> bf16 hi/lo pair
// ---------------------------------------------------------------------------
__global__ void init_x_kernel(const float* __restrict__ qe, const float* __restrict__ pos,
                              __bf16* __restrict__ xh, __bf16* __restrict__ xl)
{
  size_t i = ((size_t)blockIdx.x * 256 + threadIdx.x) * 8;
  float4 a0 = *(const float4*)(qe + i);
  float4 a1 = *(const float4*)(qe + i + 4);
  size_t pi = i & (size_t)(S_*D_ - 1);
  float4 p0 = *(const float4*)(pos + pi);
  float4 p1 = *(const float4*)(pos + pi + 4);
  float v[8] = {a0.x+p0.x, a0.y+p0.y, a0.z+p0.z, a0.w+p0.w,
                a1.x+p1.x, a1.y+p1.y, a1.z+p1.z, a1.w+p1.w};
  bfx8 hv8, lv8;
  #pragma unroll
  for (int j = 0; j < 8; ++j) {
    __bf16 hv = (__bf16)v[j];
    hv8[j] = hv;
    lv8[j] = (__bf16)(v[j] - (float)hv);
  }
  *(bfx8*)(xh + i) = hv8;
  *(bfx8*)(xl + i) = lv8;
}

// ---------------------------------------------------------------------------
// weight transpose + hi/lo split:  W[K][N] fp32  ->  T{h,l}[N][K] bf16
// ---------------------------------------------------------------------------
__global__ void transpose_split_kernel(const float* __restrict__ Wsrc,
                                       __bf16* __restrict__ Th, __bf16* __restrict__ Tl,
                                       int K, int N)
{
  __shared__ float tile[32][33];
  int n0 = blockIdx.x * 32, k0 = blockIdx.y * 32;
  int tx = threadIdx.x & 31, ty8 = threadIdx.x >> 5;  // 0..7
  #pragma unroll
  for (int j = 0; j < 4; ++j) {
    int k = ty8 + j*8;
    tile[k][tx] = Wsrc[(size_t)(k0 + k) * N + n0 + tx];
  }
  __syncthreads();
  #pragma unroll
  for (int j = 0; j < 4; ++j) {
    int n = ty8 + j*8;
    float vv = tile[tx][n];           // = W[k0+tx][n0+n]
    size_t dst = (size_t)(n0 + n) * K + k0 + tx;
    __bf16 hv = (__bf16)vv;
    Th[dst] = hv;
    Tl[dst] = (__bf16)(vv - (float)hv);
  }
}

// ---------------------------------------------------------------------------
// split-3 GEMM: C[M,N] = A[M,K] @ Bt[N,K]^T + bias; output bf16 hi/lo pair.
// flags: 1 = relu, 4 = stage A from fp32 (Afa[m] + Afp[m mod S]) on the fly
//            (fused y = interaction_emb + pos for the V projection)
// 128x128x32 tile, 4 waves, each wave a 64x64 quadrant (16 MFMA tiles).
// ---------------------------------------------------------------------------
__global__ __launch_bounds__(256, 2)
void gemm_split3_kernel(const __bf16* __restrict__ Ah, const __bf16* __restrict__ Al,
                        const float* __restrict__ Afa, const float* __restrict__ Afp,
                        const __bf16* __restrict__ Bth, const __bf16* __restrict__ Btl,
                        const float* __restrict__ bias,
                        __bf16* __restrict__ Ch, __bf16* __restrict__ Cl,
                        int M, int N, int K, int flags)
{
  constexpr int LDT = 40;   // 32 + 8 pad (bf16 elems), keeps 16B alignment
  __shared__ __bf16 sAh[128*LDT], sAl[128*LDT], sBh[128*LDT], sBl[128*LDT];
  const int t = threadIdx.x;
  const int w = t >> 6, lane = t & 63;
  const int q4 = lane >> 4, r16 = lane & 15;
  const int m0 = blockIdx.y * 128, n0 = blockIdx.x * 128;
  const int wm = (w >> 1) * 64, wn = (w & 1) * 64;

  floatx4 acc[4][4];
  #pragma unroll
  for (int i = 0; i < 4; ++i)
    #pragma unroll
    for (int j = 0; j < 4; ++j)
      acc[i][j] = (floatx4){0.f, 0.f, 0.f, 0.f};

  const int srow = t >> 2;          // 0..63
  const int scol = (t & 3) * 8;     // 0,8,16,24

  for (int k0 = 0; k0 < K; k0 += 32) {
    __syncthreads();
    #pragma unroll
    for (int c = 0; c < 2; ++c) {
      int row = srow + c * 64;
      bfx8 hv8, lv8;
      if (flags & 4) {
        size_t ga = (size_t)(m0 + row) * K + k0 + scol;
        size_t gp = (size_t)((m0 + row) & (S_ - 1)) * K + k0 + scol;
        float4 e0 = *(const float4*)&Afa[ga];
        float4 e1 = *(const float4*)&Afa[ga + 4];
        float4 p0 = *(const float4*)&Afp[gp];
        float4 p1 = *(const float4*)&Afp[gp + 4];
        float sv[8] = {e0.x+p0.x, e0.y+p0.y, e0.z+p0.z, e0.w+p0.w,
                       e1.x+p1.x, e1.y+p1.y, e1.z+p1.z, e1.w+p1.w};
        #pragma unroll
        for (int j = 0; j < 8; ++j) {
          __bf16 hv = (__bf16)sv[j];
          hv8[j] = hv;
          lv8[j] = (__bf16)(sv[j] - (float)hv);
        }
      } else {
        size_t ga = (size_t)(m0 + row) * K + k0 + scol;
        hv8 = *(const bfx8*)&Ah[ga];
        lv8 = *(const bfx8*)&Al[ga];
      }
      *(bfx8*)&sAh[row*LDT + scol] = hv8;
      *(bfx8*)&sAl[row*LDT + scol] = lv8;
      size_t gb = (size_t)(n0 + row) * K + k0 + scol;
      *(bfx8*)&sBh[row*LDT + scol] = *(const bfx8*)&Bth[gb];
      *(bfx8*)&sBl[row*LDT + scol] = *(const bfx8*)&Btl[gb];
    }
    __syncthreads();
    bfx8 af[4][2], bfr[4][2];
    #pragma unroll
    for (int i = 0; i < 4; ++i) {
      int ar = wm + i*16 + r16;
      af[i][0] = *(const bfx8*)&sAh[ar*LDT + q4*8];
      af[i][1] = *(const bfx8*)&sAl[ar*LDT + q4*8];
      int br = wn + i*16 + r16;
      bfr[i][0] = *(const bfx8*)&sBh[br*LDT + q4*8];
      bfr[i][1] = *(const bfx8*)&sBl[br*LDT + q4*8];
    }
    #pragma unroll
    for (int i = 0; i < 4; ++i)
      #pragma unroll
      for (int j = 0; j < 4; ++j) {
        acc[i][j] = mfma_bf16(af[i][0], bfr[j][0], acc[i][j]);
        acc[i][j] = mfma_bf16(af[i][0], bfr[j][1], acc[i][j]);
        acc[i][j] = mfma_bf16(af[i][1], bfr[j][0], acc[i][j]);
      }
  }

  // epilogue (C/D layout: col = lane&15, row = (lane>>4)*4 + reg  [m89-verified])
  #pragma unroll
  for (int i = 0; i < 4; ++i)
    #pragma unroll
    for (int j = 0; j < 4; ++j) {
      int gn = n0 + wn + j*16 + r16;
      float bb = bias[gn];
      #pragma unroll
      for (int r = 0; r < 4; ++r) {
        int gm = m0 + wm + i*16 + q4*4 + r;
        float val = acc[i][j][r] + bb;
        if (flags & 1) val = fmaxf(val, 0.f);
        size_t co = (size_t)gm * N + gn;
        __bf16 hv = (__bf16)val;
        Ch[co] = hv;
        Cl[co] = (__bf16)(val - (float)hv);
      }
    }
}

// ---------------------------------------------------------------------------
// attention: one block per (qt, h, b); 16 queries/block. qt reversed so
// heavy (large-nkt) blocks dispatch first.
// phase 1: scores via MFMA (split-3), causal mask, -> LDS fp32 rows
// phase 2: softmax + exact top-5 threshold + re-softmax, fully unrolled
//          (static bounds keep p[8] in VGPRs — scratch spill killed 780us)
// phase 3: O^T = V^T @ P^T via swapped MFMA operands (V staged [key][dh],
//          coalesced, no transpose scatter -> no 8-way bank conflicts)
// ---------------------------------------------------------------------------
__global__ __launch_bounds__(256, 2)
void attn_kernel(const __bf16* __restrict__ qh, const __bf16* __restrict__ ql,
                 const __bf16* __restrict__ vh, const __bf16* __restrict__ vl,
                 __bf16* __restrict__ oh, __bf16* __restrict__ ol)
{
  constexpr int LSS = 516;                       // fp32 row stride (pad 4)
  constexpr int LDV = 72;                        // bf16 row stride, 16B-mult
  __shared__ float  Ssc[16*LSS];                 // 33 KB score/prob rows
  __shared__ __bf16 KVh[64*LDV];                 // K tile / V tile [key][dh]
  __shared__ __bf16 KVl[64*LDV];
  const int qt = 31 - (int)blockIdx.x;           // heavy tiles first
  const int hd = blockIdx.y, b = blockIdx.z;
  const int t = threadIdx.x, w = t >> 6, lane = t & 63;
  const int q4 = lane >> 4, r16 = lane & 15;
  const int nkt = (qt >> 2) + 1;                 // 64-key tiles needed (causal)

  // Q fragments (A operand): rows qt*16+[0,16), cols hd*64+[0,64)
  bfx8 qf[2][2];
  {
    size_t base = ((size_t)(b*S_ + qt*16 + r16)) * D_ + hd*64;
    #pragma unroll
    for (int ks = 0; ks < 2; ++ks) {
      qf[ks][0] = *(const bfx8*)&qh[base + ks*32 + q4*8];
      qf[ks][1] = *(const bfx8*)&ql[base + ks*32 + q4*8];
    }
  }

  const int srow8 = t >> 3;        // 0..31
  const int scol8 = (t & 7) * 8;   // 0..56

  // ---- phase 1: scores ----
  for (int kt = 0; kt < nkt; ++kt) {
    __syncthreads();
    #pragma unroll
    for (int c = 0; c < 2; ++c) {     // stage K tile [64 keys][64 dh], b128
      int row = srow8 + c*32;
      size_t src = ((size_t)(b*S_ + kt*64 + row)) * D_ + hd*64 + scol8;
      *(bfx8*)&KVh[row*LDV + scol8] = *(const bfx8*)&qh[src];
      *(bfx8*)&KVl[row*LDV + scol8] = *(const bfx8*)&ql[src];
    }
    __syncthreads();
    floatx4 acc = (floatx4){0.f, 0.f, 0.f, 0.f};
    #pragma unroll
    for (int ks = 0; ks < 2; ++ks) {
      bfx8 kbh = *(const bfx8*)&KVh[(w*16 + r16)*LDV + ks*32 + q4*8];
      bfx8 kbl = *(const bfx8*)&KVl[(w*16 + r16)*LDV + ks*32 + q4*8];
      acc = mfma_bf16(qf[ks][0], kbh, acc);
      acc = mfma_bf16(qf[ks][0], kbl, acc);
      acc = mfma_bf16(qf[ks][1], kbh, acc);
    }
    int gcol = kt*64 + w*16 + r16;
    #pragma unroll
    for (int r = 0; r < 4; ++r) {
      int lrow = q4*4 + r;
      int grow = qt*16 + lrow;
      float sc = acc[r] * 0.125f;          // / sqrt(64)
      if (gcol >= grow) sc = -1e32f;       // strictly causal (tril k=-1)
      Ssc[lrow*LSS + gcol] = sc;
    }
  }
  __syncthreads();

  // ---- phase 2: softmax + exact top-5 re-softmax (wave w owns rows w*4..+3)
  //      ALL loops static: p[8] must stay in registers.
  for (int rr = 0; rr < 4; ++rr) {
    int lrow = w*4 + rr;
    int grow = qt*16 + lrow;
    float p[8];
    float mx = -3.0e38f;
    #pragma unroll
    for (int j = 0; j < 8; ++j) {
      p[j] = (j < nkt) ? Ssc[lrow*LSS + j*64 + lane] : -1e32f;
      mx = fmaxf(mx, p[j]);
    }
    mx = wave_max(mx);
    float s = 0.f;
    #pragma unroll
    for (int j = 0; j < 8; ++j) { p[j] = __expf(p[j] - mx); s += p[j]; }
    s = wave_sum(s);
    float invs = 1.0f / s;                 // scale-invariant for selection
    #pragma unroll
    for (int j = 0; j < 8; ++j) p[j] *= invs;   // masked j: exp -> 0
    if (grow == 0) {                                   // zero_pad row
      #pragma unroll
      for (int j = 0; j < 8; ++j) if (j < nkt) Ssc[lrow*LSS + j*64 + lane] = 0.f;
      continue;
    }
    if (grow <= 5) {                                   // row <= K_INDEX: plain
      #pragma unroll
      for (int j = 0; j < 8; ++j) if (j < nkt) Ssc[lrow*LSS + j*64 + lane] = p[j];
      continue;
    }
    // exact 5th order statistic (with duplicates, matching lax.top_k)
    unsigned rm = 0;
    float pmax = 0.f, thr = 0.f;
    for (int it = 0; it < 5; ++it) {
      float loc = -1.f; int locj = 0;
      #pragma unroll
      for (int j = 0; j < 8; ++j)
        if (!((rm >> j) & 1u) && p[j] > loc) { loc = p[j]; locj = j; }
      float wmx = wave_max(loc);
      if (it == 0) pmax = wmx;
      thr = wmx;
      unsigned long long ball = __ballot(loc == wmx);
      int first = (int)__builtin_ctzll(ball);          // remove one instance
      if (lane == first) rm |= 1u << locj;
    }
    float s2 = 0.f;
    #pragma unroll
    for (int j = 0; j < 8; ++j) {
      float vv = (p[j] - thr >= 0.f) ? __expf(p[j] - pmax) : 0.f;
      p[j] = vv; s2 += vv;
    }
    s2 = wave_sum(s2);
    float invs2 = 1.0f / s2;
    #pragma unroll
    for (int j = 0; j < 8; ++j) if (j < nkt) Ssc[lrow*LSS + j*64 + lane] = p[j] * invs2;
  }

  // ---- phase 3: O^T = V^T @ P^T (swapped operands) ----
  floatx4 oacc = (floatx4){0.f, 0.f, 0.f, 0.f};
  for (int vt = 0; vt < nkt; ++vt) {
    __syncthreads();
    #pragma unroll
    for (int c = 0; c < 2; ++c) {     // stage V tile [64 keys][64 dh], b128
      int row = srow8 + c*32;
      size_t src = ((size_t)(b*S_ + vt*64 + row)) * D_ + hd*64 + scol8;
      *(bfx8*)&KVh[row*LDV + scol8] = *(const bfx8*)&vh[src];
      *(bfx8*)&KVl[row*LDV + scol8] = *(const bfx8*)&vl[src];
    }
    __syncthreads();
    #pragma unroll
    for (int ks = 0; ks < 2; ++ks) {
      // A-frag: V^T[m=dh_local][k=key_local] via scalar reads of [key][dh]
      bfx8 vfh, vfl;
      #pragma unroll
      for (int j = 0; j < 8; ++j) {
        int kk = (ks*32 + q4*8 + j)*LDV + w*16 + r16;
        vfh[j] = KVh[kk];
        vfl[j] = KVl[kk];
      }
      // B-frag: P^T[k][n=q] = P[q=r16][key], vector fp32 reads + hi/lo split
      const float* pr = &Ssc[r16*LSS + vt*64 + ks*32 + q4*8];
      float4 f0 = *(const float4*)pr;
      float4 f1 = *(const float4*)(pr + 4);
      float pv[8] = {f0.x,f0.y,f0.z,f0.w,f1.x,f1.y,f1.z,f1.w};
      bfx8 ph, pl;
      #pragma unroll
      for (int i = 0; i < 8; ++i) {
        __bf16 hv = (__bf16)pv[i];
        ph[i] = hv;
        pl[i] = (__bf16)(pv[i] - (float)hv);
      }
      oacc = mfma_bf16(vfh, ph, oacc);
      oacc = mfma_bf16(vfh, pl, oacc);
      oacc = mfma_bf16(vfl, ph, oacc);
    }
  }
  // D^T layout: col(lane&15) = q_local, row(q4*4+r) = dh_local in chunk w*16
  #pragma unroll
  for (int r = 0; r < 4; ++r) {
    int grow = qt*16 + r16;
    int dh  = w*16 + q4*4 + r;
    size_t off = ((size_t)(b*S_ + grow)) * D_ + hd*64 + dh;
    float val = oacc[r];
    __bf16 hv = (__bf16)val;
    oh[off] = hv;
    ol[off] = (__bf16)(val - (float)hv);
  }
}

// ---------------------------------------------------------------------------
// residual + LayerNorm (fp32): x = LN(xh+xl + th+tl); writes bf16 hi/lo pair
// and (if fout) the exact fp32 result. 1 wave/row, 4 rows/block.
// ---------------------------------------------------------------------------
__global__ void resid_ln_kernel(const __bf16* __restrict__ xhin, const __bf16* __restrict__ xlin,
                                const __bf16* __restrict__ thin, const __bf16* __restrict__ tlin,
                                const float* __restrict__ g, const float* __restrict__ bb,
                                __bf16* __restrict__ xh, __bf16* __restrict__ xl,
                                float* __restrict__ fout)
{
  int row = blockIdx.x * 4 + (threadIdx.x >> 6);
  int lane = threadIdx.x & 63;
  size_t base = (size_t)row * D_ + lane * 8;
  bfx8 h8 = *(const bfx8*)(xhin + base);
  bfx8 l8 = *(const bfx8*)(xlin + base);
  bfx8 th8 = *(const bfx8*)(thin + base);
  bfx8 tl8 = *(const bfx8*)(tlin + base);
  float v[8];
  #pragma unroll
  for (int j = 0; j < 8; ++j)
    v[j] = ((float)h8[j] + (float)l8[j]) + ((float)th8[j] + (float)tl8[j]);
  float s = 0.f;
  #pragma unroll
  for (int j = 0; j < 8; ++j) s += v[j];
  s = wave_sum(s);
  float mean = s * (1.0f/512.0f);
  float var = 0.f;
  #pragma unroll
  for (int j = 0; j < 8; ++j) { float d = v[j] - mean; var += d*d; }
  var = wave_sum(var) * (1.0f/512.0f);
  float rs = 1.0f / sqrtf(var + 1e-5f);
  float4 g0 = *(const float4*)(g + lane*8);
  float4 g1 = *(const float4*)(g + lane*8 + 4);
  float4 b0 = *(const float4*)(bb + lane*8);
  float4 b1 = *(const float4*)(bb + lane*8 + 4);
  float gg[8]  = {g0.x,g0.y,g0.z,g0.w,g1.x,g1.y,g1.z,g1.w};
  float bbv[8] = {b0.x,b0.y,b0.z,b0.w,b1.x,b1.y,b1.z,b1.w};
  float o[8];
  #pragma unroll
  for (int j = 0; j < 8; ++j) o[j] = (v[j] - mean) * rs * gg[j] + bbv[j];
  bfx8 hv8, lv8;
  #pragma unroll
  for (int j = 0; j < 8; ++j) {
    __bf16 hv = (__bf16)o[j];
    hv8[j] = hv;
    lv8[j] = (__bf16)(o[j] - (float)hv);
  }
  *(bfx8*)(xh + base) = hv8;
  *(bfx8*)(xl + base) = lv8;
  if (fout) {
    *(float4*)(fout + base)     = make_float4(o[0],o[1],o[2],o[3]);
    *(float4*)(fout + base + 4) = make_float4(o[4],o[5],o[6],o[7]);
  }
}

// ---------------------------------------------------------------------------
extern "C" void kernel_launch(void* const* d_in, const int* in_sizes, int n_in,
                              void* d_out, int out_size, void* d_ws, size_t ws_size,
                              hipStream_t stream)
{
  const float* qe   = (const float*)d_in[0];
  const float* ie   = (const float*)d_in[1];
  const float* pos  = (const float*)d_in[2];
  const float* Wk   = (const float*)d_in[3];
  const float* bk   = (const float*)d_in[4];
  const float* Wv   = (const float*)d_in[5];
  const float* bv   = (const float*)d_in[6];
  const float* Wo   = (const float*)d_in[7];
  const float* bo   = (const float*)d_in[8];
  const float* ln1g = (const float*)d_in[9];
  const float* ln1b = (const float*)d_in[10];
  const float* W1   = (const float*)d_in[11];
  const float* b1   = (const float*)d_in[12];
  const float* W2   = (const float*)d_in[13];
  const float* b2   = (const float*)d_in[14];
  const float* ln2g = (const float*)d_in[15];
  const float* ln2b = (const float*)d_in[16];

  char* wsp = (char*)d_ws;
  size_t off = 0;
  auto alloc = [&](size_t bytes) -> void* {
    void* p = wsp + off;
    off += (bytes + 255) & ~(size_t)255;
    return p;
  };
  const size_t NB = (size_t)BS_ * D_ * sizeof(__bf16);   // 16 MB per bf16 activation
  __bf16* xh  = (__bf16*)alloc(NB);
  __bf16* xl  = (__bf16*)alloc(NB);
  // q region aliases t (attn-out-proj / FFN2 result): q dead once out-proj runs
  char*   qt_ = (char*)  alloc(2*NB);
  __bf16* qhb = (__bf16*)qt_;
  __bf16* qlb = (__bf16*)(qt_ + NB);
  __bf16* thb = (__bf16*)qt_;
  __bf16* tlb = (__bf16*)(qt_ + NB);
  __bf16* vhb = (__bf16*)alloc(NB);
  __bf16* vlb = (__bf16*)alloc(NB);
  // o region aliases FFN hidden (M=4096 chunk: 4096*2048*2 B = NB each)
  char*   oh_ = (char*) alloc(2*NB);
  __bf16* ohb = (__bf16*)oh_;
  __bf16* olb = (__bf16*)(oh_ + NB);
  __bf16* hhb = (__bf16*)oh_;
  __bf16* hlb = (__bf16*)(oh_ + NB);
  const size_t LW = 3*(size_t)D_*D_ + 2*(size_t)D_*DFF_;   // elems / layer
  __bf16* wth = (__bf16*)alloc(2*LW*sizeof(__bf16));
  __bf16* wtl = (__bf16*)alloc(2*LW*sizeof(__bf16));
  float*  xout = (float*)d_out;
  // total ws usage ~151 MB

  const size_t OK = 0, OV = (size_t)D_*D_, OO = 2*(size_t)D_*D_;
  const size_t O1 = 3*(size_t)D_*D_, O2 = 3*(size_t)D_*D_ + (size_t)D_*DFF_;

  // weight transposes + splits (recomputed each call; graph-capture safe)
  for (int l = 0; l < L_; ++l) {
    size_t base = (size_t)l * LW;
    transpose_split_kernel<<<dim3(16,16), 256, 0, stream>>>(Wk + (size_t)l*D_*D_,   wth+base+OK, wtl+base+OK, D_,  D_);
    transpose_split_kernel<<<dim3(16,16), 256, 0, stream>>>(Wv + (size_t)l*D_*D_,   wth+base+OV, wtl+base+OV, D_,  D_);
    transpose_split_kernel<<<dim3(16,16), 256, 0, stream>>>(Wo + (size_t)l*D_*D_,   wth+base+OO, wtl+base+OO, D_,  D_);
    transpose_split_kernel<<<dim3(64,16), 256, 0, stream>>>(W1 + (size_t)l*D_*DFF_, wth+base+O1, wtl+base+O1, D_,  DFF_);
    transpose_split_kernel<<<dim3(16,64), 256, 0, stream>>>(W2 + (size_t)l*DFF_*D_, wth+base+O2, wtl+base+O2, DFF_, D_);
  }

  init_x_kernel<<<4096, 256, 0, stream>>>(qe, pos, xh, xl);

  for (int l = 0; l < L_; ++l) {
    size_t base = (size_t)l * LW;
    // q = k = x @ Wk + bk (kq_same), bf16 hi/lo out
    gemm_split3_kernel<<<dim3(4,128), 256, 0, stream>>>(xh, xl, nullptr, nullptr,
        wth+base+OK, wtl+base+OK, bk + (size_t)l*D_, qhb, qlb, BS_, D_, D_, 0);
    // v = (ie + pos) @ Wv + bv  (fused y staging from fp32)
    gemm_split3_kernel<<<dim3(4,128), 256, 0, stream>>>(nullptr, nullptr, ie, pos,
        wth+base+OV, wtl+base+OV, bv + (size_t)l*D_, vhb, vlb, BS_, D_, D_, 4);
    // sparse attention
    attn_kernel<<<dim3(S_/16, H_, B_), 256, 0, stream>>>(qhb, qlb, vhb, vlb, ohb, olb);
    // out-proj -> t (hi/lo; overwrites q region, q is dead)
    gemm_split3_kernel<<<dim3(4,128), 256, 0, stream>>>(ohb, olb, nullptr, nullptr,
        wth+base+OO, wtl+base+OO, bo + (size_t)l*D_, thb, tlb, BS_, D_, D_, 0);
    // x = LN1(x + t)
    resid_ln_kernel<<<BS_/4, 256, 0, stream>>>(xh, xl, thb, tlb,
        ln1g + (size_t)l*D_, ln1b + (size_t)l*D_, xh, xl, nullptr);
    // FFN in four M=4096 chunks (hidden aliases o region, out -> t region)
    for (int ch = 0; ch < 4; ++ch) {
      size_t ao = (size_t)ch*4096*D_;
      gemm_split3_kernel<<<dim3(16,32), 256, 0, stream>>>(xh + ao, xl + ao, nullptr, nullptr,
          wth+base+O1, wtl+base+O1, b1 + (size_t)l*DFF_, hhb, hlb, 4096, DFF_, D_, 1);
      gemm_split3_kernel<<<dim3(4,32), 256, 0, stream>>>(hhb, hlb, nullptr, nullptr,
          wth+base+O2, wtl+base+O2, b2 + (size_t)l*D_, thb + ao, tlb + ao, 4096, D_, DFF_, 0);
    }
    // x = LN2(x + t); final layer writes fp32 straight to d_out
    resid_ln_kernel<<<BS_/4, 256, 0, stream>>>(xh, xl, thb, tlb,
        ln2g + (size_t)l*D_, ln2b + (size_t)l*D_, xh, xl,
        (l == L_-1) ? xout : nullptr);
  }
}

// Round 5
// 1484.843 us; speedup vs baseline: 1.9480x; 1.3872x over previous
//
#include <hip/hip_runtime.h>

// ---------------------------------------------------------------------------
// SparseKT forward, MI355X gfx950. I/O dtype: fp32 (per reference).
// Numerics: fp32 tensors decomposed into hi/lo bf16 pairs (pseudo-fp32,
// rel err ~2^-17). GEMMs are split-3: C = Ah*Bh + Ah*Bl + Al*Bh (3 MFMAs).
// Softmax / exact top-5 / LayerNorm in fp32. Residual stream: hi/lo pairs.
// R4->R5: (a) attn: XCD-affine grid swizzle (b == xcd mod 8 -> K/V L2-resident)
//         + register-prefetch double buffering of K/V tiles (FETCH 245MB was
//         cross-XCD re-fetch; kernel was fetch-latency-bound at 10% HBM);
//         (b) GEMM: global_load_lds width-16 staging + XOR-swizzled LDS
//         (conflict-free b128 frag reads, no padding needed);
//         (c) FFN chunks M=8192 (FFN2 grid 128->256 blocks).
// ---------------------------------------------------------------------------

#define L_   2
#define B_   32
#define S_   512
#define D_   512
#define H_   8
#define DH_  64
#define DFF_ 2048
#define BS_  (B_*S_)      // 16384

typedef __bf16 bfx8 __attribute__((ext_vector_type(8)));
typedef float floatx4 __attribute__((ext_vector_type(4)));

__device__ __forceinline__ floatx4 mfma_bf16(bfx8 a, bfx8 b, floatx4 c) {
  return __builtin_amdgcn_mfma_f32_16x16x32_bf16(a, b, c, 0, 0, 0);
}

__device__ __forceinline__ float wave_sum(float v) {
  #pragma unroll
  for (int d = 32; d > 0; d >>= 1) v += __shfl_xor(v, d);
  return v;
}
__device__ __forceinline__ float wave_max(float v) {
  #pragma unroll
  for (int d = 32; d > 0; d >>= 1) v = fmaxf(v, __shfl_xor(v, d));
  return v;
}

// async global->LDS, 16 B per lane; LDS dest = wave-uniform base + lane*16
__device__ __forceinline__ void lds_load16(__bf16* lds, const __bf16* g) {
  __builtin_amdgcn_global_load_lds(
      (const __attribute__((address_space(1))) unsigned int*)g,
      (__attribute__((address_space(3))) unsigned int*)lds, 16, 0, 0);
}

// LDS chunk swizzle: logical 8-elem chunk q of row r stored at q ^ ((r>>1)&3)
__device__ __forceinline__ int swz(int row, int q) { return q ^ ((row >> 1) & 3); }

// ---------------------------------------------------------------------------
// init: x = question_emb + pos (fp32) -> bf16 hi/lo pair
// ---------------------------------------------------------------------------
__global__ void init_x_kernel(const float* __restrict__ qe, const float* __restrict__ pos,
                              __bf16* __restrict__ xh, __bf16* __restrict__ xl)
{
  size_t i = ((size_t)blockIdx.x * 256 + threadIdx.x) * 8;
  float4 a0 = *(const float4*)(qe + i);
  float4 a1 = *(const float4*)(qe + i + 4);
  size_t pi = i & (size_t)(S_*D_ - 1);
  float4 p0 = *(const float4*)(pos + pi);
  float4 p1 = *(const float4*)(pos + pi + 4);
  float v[8] = {a0.x+p0.x, a0.y+p0.y, a0.z+p0.z, a0.w+p0.w,
                a1.x+p1.x, a1.y+p1.y, a1.z+p1.z, a1.w+p1.w};
  bfx8 hv8, lv8;
  #pragma unroll
  for (int j = 0; j < 8; ++j) {
    __bf16 hv = (__bf16)v[j];
    hv8[j] = hv;
    lv8[j] = (__bf16)(v[j] - (float)hv);
  }
  *(bfx8*)(xh + i) = hv8;
  *(bfx8*)(xl + i) = lv8;
}

// ---------------------------------------------------------------------------
// weight transpose + hi/lo split:  W[K][N] fp32  ->  T{h,l}[N][K] bf16
// ---------------------------------------------------------------------------
__global__ void transpose_split_kernel(const float* __restrict__ Wsrc,
                                       __bf16* __restrict__ Th, __bf16* __restrict__ Tl,
                                       int K, int N)
{
  __shared__ float tile[32][33];
  int n0 = blockIdx.x * 32, k0 = blockIdx.y * 32;
  int tx = threadIdx.x & 31, ty8 = threadIdx.x >> 5;  // 0..7
  #pragma unroll
  for (int j = 0; j < 4; ++j) {
    int k = ty8 + j*8;
    tile[k][tx] = Wsrc[(size_t)(k0 + k) * N + n0 + tx];
  }
  __syncthreads();
  #pragma unroll
  for (int j = 0; j < 4; ++j) {
    int n = ty8 + j*8;
    float vv = tile[tx][n];           // = W[k0+tx][n0+n]
    size_t dst = (size_t)(n0 + n) * K + k0 + tx;
    __bf16 hv = (__bf16)vv;
    Th[dst] = hv;
    Tl[dst] = (__bf16)(vv - (float)hv);
  }
}

// ---------------------------------------------------------------------------
// split-3 GEMM: C[M,N] = A[M,K] @ Bt[N,K]^T + bias; output bf16 hi/lo pair.
// flags: 1 = relu, 4 = stage A from fp32 (Afa[m] + Afp[m mod S]) on the fly
// 128x128x32 tile, 4 waves (64x64 quadrant each, 16 MFMA tiles).
// Fast path (no flag 4): wave w DMA-stages buffer w via global_load_lds x8.
// LDS XOR-swizzled (swz) -> conflict-free ds_read_b128 fragments, no padding.
// ---------------------------------------------------------------------------
__global__ __launch_bounds__(256, 2)
void gemm_split3_kernel(const __bf16* __restrict__ Ah, const __bf16* __restrict__ Al,
                        const float* __restrict__ Afa, const float* __restrict__ Afp,
                        const __bf16* __restrict__ Bth, const __bf16* __restrict__ Btl,
                        const float* __restrict__ bias,
                        __bf16* __restrict__ Ch, __bf16* __restrict__ Cl,
                        int M, int N, int K, int flags)
{
  __shared__ __bf16 sAh[128*32], sAl[128*32], sBh[128*32], sBl[128*32];
  const int t = threadIdx.x;
  const int w = t >> 6, lane = t & 63;
  const int q4 = lane >> 4, r16 = lane & 15;
  const int m0 = blockIdx.y * 128, n0 = blockIdx.x * 128;
  const int wm = (w >> 1) * 64, wn = (w & 1) * 64;

  floatx4 acc[4][4];
  #pragma unroll
  for (int i = 0; i < 4; ++i)
    #pragma unroll
    for (int j = 0; j < 4; ++j)
      acc[i][j] = (floatx4){0.f, 0.f, 0.f, 0.f};

  // fast-path per-wave staging assignment: wave w stages buffer w
  const __bf16* wsrc = (w == 0) ? Ah : (w == 1) ? Al : (w == 2) ? Bth : Btl;
  __bf16* wdst = (w == 0) ? sAh : (w == 1) ? sAl : (w == 2) ? sBh : sBl;
  const int rbase = (w < 2) ? m0 : n0;
  const int rl = lane >> 2;        // row within 16-row group
  const int cp = lane & 3;         // physical chunk this lane fills

  // manual-path (flags&4) mapping
  const int srow = t >> 2;          // 0..63
  const int sq   = t & 3;           // logical chunk

  for (int k0 = 0; k0 < K; k0 += 32) {
    __syncthreads();
    if (!(flags & 4)) {
      #pragma unroll
      for (int g = 0; g < 8; ++g) {
        int row = g*16 + rl;
        int ql = swz(row, cp);       // logical chunk landing at phys cp
        const __bf16* gp = wsrc + (size_t)(rbase + row) * K + k0 + ql*8;
        lds_load16(wdst + g*512, gp);
      }
    } else {
      #pragma unroll
      for (int c = 0; c < 2; ++c) {
        int row = srow + c * 64;
        size_t ga = (size_t)(m0 + row) * K + k0 + sq*8;
        size_t gp = (size_t)((m0 + row) & (S_ - 1)) * K + k0 + sq*8;
        float4 e0 = *(const float4*)&Afa[ga];
        float4 e1 = *(const float4*)&Afa[ga + 4];
        float4 p0 = *(const float4*)&Afp[gp];
        float4 p1 = *(const float4*)&Afp[gp + 4];
        float sv[8] = {e0.x+p0.x, e0.y+p0.y, e0.z+p0.z, e0.w+p0.w,
                       e1.x+p1.x, e1.y+p1.y, e1.z+p1.z, e1.w+p1.w};
        bfx8 hv8, lv8;
        #pragma unroll
        for (int j = 0; j < 8; ++j) {
          __bf16 hv = (__bf16)sv[j];
          hv8[j] = hv;
          lv8[j] = (__bf16)(sv[j] - (float)hv);
        }
        int pc = swz(row, sq);
        *(bfx8*)&sAh[row*32 + pc*8] = hv8;
        *(bfx8*)&sAl[row*32 + pc*8] = lv8;
        size_t gb = (size_t)(n0 + row) * K + k0 + sq*8;
        *(bfx8*)&sBh[row*32 + pc*8] = *(const bfx8*)&Bth[gb];
        *(bfx8*)&sBl[row*32 + pc*8] = *(const bfx8*)&Btl[gb];
      }
    }
    __syncthreads();
    bfx8 af[4][2], bfr[4][2];
    #pragma unroll
    for (int i = 0; i < 4; ++i) {
      int ar = wm + i*16 + r16;
      int sa = swz(ar, q4) * 8;
      af[i][0] = *(const bfx8*)&sAh[ar*32 + sa];
      af[i][1] = *(const bfx8*)&sAl[ar*32 + sa];
      int br = wn + i*16 + r16;
      int sb = swz(br, q4) * 8;
      bfr[i][0] = *(const bfx8*)&sBh[br*32 + sb];
      bfr[i][1] = *(const bfx8*)&sBl[br*32 + sb];
    }
    #pragma unroll
    for (int i = 0; i < 4; ++i)
      #pragma unroll
      for (int j = 0; j < 4; ++j) {
        acc[i][j] = mfma_bf16(af[i][0], bfr[j][0], acc[i][j]);
        acc[i][j] = mfma_bf16(af[i][0], bfr[j][1], acc[i][j]);
        acc[i][j] = mfma_bf16(af[i][1], bfr[j][0], acc[i][j]);
      }
  }

  // epilogue (C/D layout: col = lane&15, row = (lane>>4)*4 + reg  [m89-verified])
  #pragma unroll
  for (int i = 0; i < 4; ++i)
    #pragma unroll
    for (int j = 0; j < 4; ++j) {
      int gn = n0 + wn + j*16 + r16;
      float bb = bias[gn];
      #pragma unroll
      for (int r = 0; r < 4; ++r) {
        int gm = m0 + wm + i*16 + q4*4 + r;
        float val = acc[i][j][r] + bb;
        if (flags & 1) val = fmaxf(val, 0.f);
        size_t co = (size_t)gm * N + gn;
        __bf16 hv = (__bf16)val;
        Ch[co] = hv;
        Cl[co] = (__bf16)(val - (float)hv);
      }
    }
}

// ---------------------------------------------------------------------------
// attention: 1-D grid 8192, decoded so batch b == XCD (lin&7): K/V of a batch
// stay L2-resident on one XCD. Heavy q-tiles first within each XCD.
// phase 1: scores via MFMA (split-3), register-prefetched K tiles
// phase 2: softmax + exact top-5 re-softmax, fully static (regs)
// phase 3: O^T = V^T @ P^T, register-prefetched V tiles (tile0 prefetched
//          before phase 2 to hide latency under softmax)
// ---------------------------------------------------------------------------
__global__ __launch_bounds__(256, 2)
void attn_kernel(const __bf16* __restrict__ qh, const __bf16* __restrict__ ql,
                 const __bf16* __restrict__ vh, const __bf16* __restrict__ vl,
                 __bf16* __restrict__ oh, __bf16* __restrict__ ol)
{
  constexpr int LSS = 516;                       // fp32 row stride (pad 4)
  constexpr int LDV = 72;                        // bf16 row stride, 16B-mult
  __shared__ float  Ssc[16*LSS];                 // 33 KB score/prob rows
  __shared__ __bf16 KVh[64*LDV];                 // K tile / V tile [key][dh]
  __shared__ __bf16 KVl[64*LDV];
  const int lin = blockIdx.x;
  const int xcd = lin & 7;
  const int ord = lin >> 3;                      // 0..1023 per xcd
  const int qt  = 31 - (ord & 31);               // heavy tiles first
  const int bh  = ord >> 5;                      // 0..31
  const int hd  = bh & 7;
  const int b   = ((bh >> 3) << 3) | xcd;        // b mod 8 == xcd
  const int t = threadIdx.x, w = t >> 6, lane = t & 63;
  const int q4 = lane >> 4, r16 = lane & 15;
  const int nkt = (qt >> 2) + 1;                 // 64-key tiles (causal)

  // Q fragments (A operand): rows qt*16+[0,16), cols hd*64+[0,64)
  bfx8 qf[2][2];
  {
    size_t base = ((size_t)(b*S_ + qt*16 + r16)) * D_ + hd*64;
    #pragma unroll
    for (int ks = 0; ks < 2; ++ks) {
      qf[ks][0] = *(const bfx8*)&qh[base + ks*32 + q4*8];
      qf[ks][1] = *(const bfx8*)&ql[base + ks*32 + q4*8];
    }
  }

  const int srow8 = t >> 3;        // 0..31
  const int scol8 = (t & 7) * 8;   // 0..56

  bfx8 pf_h[2], pf_l[2];           // prefetch registers (K or V tile)
  auto loadK = [&](int kt) {
    #pragma unroll
    for (int c = 0; c < 2; ++c) {
      int row = srow8 + c*32;
      size_t src = ((size_t)(b*S_ + kt*64 + row)) * D_ + hd*64 + scol8;
      pf_h[c] = *(const bfx8*)&qh[src];
      pf_l[c] = *(const bfx8*)&ql[src];
    }
  };
  auto loadV = [&](int vt) {
    #pragma unroll
    for (int c = 0; c < 2; ++c) {
      int row = srow8 + c*32;
      size_t src = ((size_t)(b*S_ + vt*64 + row)) * D_ + hd*64 + scol8;
      pf_h[c] = *(const bfx8*)&vh[src];
      pf_l[c] = *(const bfx8*)&vl[src];
    }
  };

  // ---- phase 1: scores ----
  loadK(0);
  for (int kt = 0; kt < nkt; ++kt) {
    #pragma unroll
    for (int c = 0; c < 2; ++c) {
      int row = srow8 + c*32;
      *(bfx8*)&KVh[row*LDV + scol8] = pf_h[c];
      *(bfx8*)&KVl[row*LDV + scol8] = pf_l[c];
    }
    __syncthreads();
    if (kt + 1 < nkt) loadK(kt + 1);   // overlap next fetch with MFMA
    floatx4 acc = (floatx4){0.f, 0.f, 0.f, 0.f};
    #pragma unroll
    for (int ks = 0; ks < 2; ++ks) {
      bfx8 kbh = *(const bfx8*)&KVh[(w*16 + r16)*LDV + ks*32 + q4*8];
      bfx8 kbl = *(const bfx8*)&KVl[(w*16 + r16)*LDV + ks*32 + q4*8];
      acc = mfma_bf16(qf[ks][0], kbh, acc);
      acc = mfma_bf16(qf[ks][0], kbl, acc);
      acc = mfma_bf16(qf[ks][1], kbh, acc);
    }
    int gcol = kt*64 + w*16 + r16;
    #pragma unroll
    for (int r = 0; r < 4; ++r) {
      int lrow = q4*4 + r;
      int grow = qt*16 + lrow;
      float sc = acc[r] * 0.125f;          // / sqrt(64)
      if (gcol >= grow) sc = -1e32f;       // strictly causal (tril k=-1)
      Ssc[lrow*LSS + gcol] = sc;
    }
    __syncthreads();
  }

  loadV(0);                                // hide V tile 0 under softmax

  // ---- phase 2: softmax + exact top-5 re-softmax (wave w owns rows w*4..+3)
  for (int rr = 0; rr < 4; ++rr) {
    int lrow = w*4 + rr;
    int grow = qt*16 + lrow;
    float p[8];
    float mx = -3.0e38f;
    #pragma unroll
    for (int j = 0; j < 8; ++j) {
      p[j] = (j < nkt) ? Ssc[lrow*LSS + j*64 + lane] : -1e32f;
      mx = fmaxf(mx, p[j]);
    }
    mx = wave_max(mx);
    float s = 0.f;
    #pragma unroll
    for (int j = 0; j < 8; ++j) { p[j] = __expf(p[j] - mx); s += p[j]; }
    s = wave_sum(s);
    float invs = 1.0f / s;
    #pragma unroll
    for (int j = 0; j < 8; ++j) p[j] *= invs;   // masked j: exp -> 0
    if (grow == 0) {                                   // zero_pad row
      #pragma unroll
      for (int j = 0; j < 8; ++j) if (j < nkt) Ssc[lrow*LSS + j*64 + lane] = 0.f;
      continue;
    }
    if (grow <= 5) {                                   // row <= K_INDEX: plain
      #pragma unroll
      for (int j = 0; j < 8; ++j) if (j < nkt) Ssc[lrow*LSS + j*64 + lane] = p[j];
      continue;
    }
    // exact 5th order statistic (with duplicates, matching lax.top_k)
    unsigned rm = 0;
    float pmax = 0.f, thr = 0.f;
    for (int it = 0; it < 5; ++it) {
      float loc = -1.f; int locj = 0;
      #pragma unroll
      for (int j = 0; j < 8; ++j)
        if (!((rm >> j) & 1u) && p[j] > loc) { loc = p[j]; locj = j; }
      float wmx = wave_max(loc);
      if (it == 0) pmax = wmx;
      thr = wmx;
      unsigned long long ball = __ballot(loc == wmx);
      int first = (int)__builtin_ctzll(ball);          // remove one instance
      if (lane == first) rm |= 1u << locj;
    }
    float s2 = 0.f;
    #pragma unroll
    for (int j = 0; j < 8; ++j) {
      float vv = (p[j] - thr >= 0.f) ? __expf(p[j] - pmax) : 0.f;
      p[j] = vv; s2 += vv;
    }
    s2 = wave_sum(s2);
    float invs2 = 1.0f / s2;
    #pragma unroll
    for (int j = 0; j < 8; ++j) if (j < nkt) Ssc[lrow*LSS + j*64 + lane] = p[j] * invs2;
  }

  // ---- phase 3: O^T = V^T @ P^T (swapped operands) ----
  floatx4 oacc = (floatx4){0.f, 0.f, 0.f, 0.f};
  for (int vt = 0; vt < nkt; ++vt) {
    #pragma unroll
    for (int c = 0; c < 2; ++c) {
      int row = srow8 + c*32;
      *(bfx8*)&KVh[row*LDV + scol8] = pf_h[c];
      *(bfx8*)&KVl[row*LDV + scol8] = pf_l[c];
    }
    __syncthreads();                  // also orders phase-2 Ssc writes
    if (vt + 1 < nkt) loadV(vt + 1);
    #pragma unroll
    for (int ks = 0; ks < 2; ++ks) {
      // A-frag: V^T[m=dh_local][k=key_local] via scalar reads of [key][dh]
      bfx8 vfh, vfl;
      #pragma unroll
      for (int j = 0; j < 8; ++j) {
        int kk = (ks*32 + q4*8 + j)*LDV + w*16 + r16;
        vfh[j] = KVh[kk];
        vfl[j] = KVl[kk];
      }
      // B-frag: P^T[k][n=q] = P[q=r16][key], vector fp32 reads + hi/lo split
      const float* pr = &Ssc[r16*LSS + vt*64 + ks*32 + q4*8];
      float4 f0 = *(const float4*)pr;
      float4 f1 = *(const float4*)(pr + 4);
      float pv[8] = {f0.x,f0.y,f0.z,f0.w,f1.x,f1.y,f1.z,f1.w};
      bfx8 ph, pl;
      #pragma unroll
      for (int i = 0; i < 8; ++i) {
        __bf16 hv = (__bf16)pv[i];
        ph[i] = hv;
        pl[i] = (__bf16)(pv[i] - (float)hv);
      }
      oacc = mfma_bf16(vfh, ph, oacc);
      oacc = mfma_bf16(vfh, pl, oacc);
      oacc = mfma_bf16(vfl, ph, oacc);
    }
    __syncthreads();
  }
  // D^T layout: col(lane&15) = q_local, row(q4*4+r) = dh_local in chunk w*16
  #pragma unroll
  for (int r = 0; r < 4; ++r) {
    int grow = qt*16 + r16;
    int dh  = w*16 + q4*4 + r;
    size_t off = ((size_t)(b*S_ + grow)) * D_ + hd*64 + dh;
    float val = oacc[r];
    __bf16 hv = (__bf16)val;
    oh[off] = hv;
    ol[off] = (__bf16)(val - (float)hv);
  }
}

// ---------------------------------------------------------------------------
// residual + LayerNorm (fp32): x = LN(xh+xl + th+tl); writes bf16 hi/lo pair
// and (if fout) the exact fp32 result. 1 wave/row, 4 rows/block.
// ---------------------------------------------------------------------------
__global__ void resid_ln_kernel(const __bf16* __restrict__ xhin, const __bf16* __restrict__ xlin,
                                const __bf16* __restrict__ thin, const __bf16* __restrict__ tlin,
                                const float* __restrict__ g, const float* __restrict__ bb,
                                __bf16* __restrict__ xh, __bf16* __restrict__ xl,
                                float* __restrict__ fout)
{
  int row = blockIdx.x * 4 + (threadIdx.x >> 6);
  int lane = threadIdx.x & 63;
  size_t base = (size_t)row * D_ + lane * 8;
  bfx8 h8 = *(const bfx8*)(xhin + base);
  bfx8 l8 = *(const bfx8*)(xlin + base);
  bfx8 th8 = *(const bfx8*)(thin + base);
  bfx8 tl8 = *(const bfx8*)(tlin + base);
  float v[8];
  #pragma unroll
  for (int j = 0; j < 8; ++j)
    v[j] = ((float)h8[j] + (float)l8[j]) + ((float)th8[j] + (float)tl8[j]);
  float s = 0.f;
  #pragma unroll
  for (int j = 0; j < 8; ++j) s += v[j];
  s = wave_sum(s);
  float mean = s * (1.0f/512.0f);
  float var = 0.f;
  #pragma unroll
  for (int j = 0; j < 8; ++j) { float d = v[j] - mean; var += d*d; }
  var = wave_sum(var) * (1.0f/512.0f);
  float rs = 1.0f / sqrtf(var + 1e-5f);
  float4 g0 = *(const float4*)(g + lane*8);
  float4 g1 = *(const float4*)(g + lane*8 + 4);
  float4 b0 = *(const float4*)(bb + lane*8);
  float4 b1 = *(const float4*)(bb + lane*8 + 4);
  float gg[8]  = {g0.x,g0.y,g0.z,g0.w,g1.x,g1.y,g1.z,g1.w};
  float bbv[8] = {b0.x,b0.y,b0.z,b0.w,b1.x,b1.y,b1.z,b1.w};
  float o[8];
  #pragma unroll
  for (int j = 0; j < 8; ++j) o[j] = (v[j] - mean) * rs * gg[j] + bbv[j];
  bfx8 hv8, lv8;
  #pragma unroll
  for (int j = 0; j < 8; ++j) {
    __bf16 hv = (__bf16)o[j];
    hv8[j] = hv;
    lv8[j] = (__bf16)(o[j] - (float)hv);
  }
  *(bfx8*)(xh + base) = hv8;
  *(bfx8*)(xl + base) = lv8;
  if (fout) {
    *(float4*)(fout + base)     = make_float4(o[0],o[1],o[2],o[3]);
    *(float4*)(fout + base + 4) = make_float4(o[4],o[5],o[6],o[7]);
  }
}

// ---------------------------------------------------------------------------
extern "C" void kernel_launch(void* const* d_in, const int* in_sizes, int n_in,
                              void* d_out, int out_size, void* d_ws, size_t ws_size,
                              hipStream_t stream)
{
  const float* qe   = (const float*)d_in[0];
  const float* ie   = (const float*)d_in[1];
  const float* pos  = (const float*)d_in[2];
  const float* Wk   = (const float*)d_in[3];
  const float* bk   = (const float*)d_in[4];
  const float* Wv   = (const float*)d_in[5];
  const float* bv   = (const float*)d_in[6];
  const float* Wo   = (const float*)d_in[7];
  const float* bo   = (const float*)d_in[8];
  const float* ln1g = (const float*)d_in[9];
  const float* ln1b = (const float*)d_in[10];
  const float* W1   = (const float*)d_in[11];
  const float* b1   = (const float*)d_in[12];
  const float* W2   = (const float*)d_in[13];
  const float* b2   = (const float*)d_in[14];
  const float* ln2g = (const float*)d_in[15];
  const float* ln2b = (const float*)d_in[16];

  char* wsp = (char*)d_ws;
  size_t off = 0;
  auto alloc = [&](size_t bytes) -> void* {
    void* p = wsp + off;
    off += (bytes + 255) & ~(size_t)255;
    return p;
  };
  const size_t NB = (size_t)BS_ * D_ * sizeof(__bf16);   // 16 MB per bf16 activation
  __bf16* xh  = (__bf16*)alloc(NB);
  __bf16* xl  = (__bf16*)alloc(NB);
  // q region aliases t (attn-out-proj / FFN2 result): q dead once out-proj runs
  char*   qt_ = (char*)  alloc(2*NB);
  __bf16* qhb = (__bf16*)qt_;
  __bf16* qlb = (__bf16*)(qt_ + NB);
  __bf16* thb = (__bf16*)qt_;
  __bf16* tlb = (__bf16*)(qt_ + NB);
  __bf16* vhb = (__bf16*)alloc(NB);
  __bf16* vlb = (__bf16*)alloc(NB);
  // o region (2*NB) aliases FFN hidden-hi (M=8192: 8192*2048*2B = 32MB = 2*NB)
  char*   oh_ = (char*) alloc(2*NB);
  __bf16* ohb = (__bf16*)oh_;
  __bf16* olb = (__bf16*)(oh_ + NB);
  __bf16* hhb = (__bf16*)oh_;
  __bf16* hlb = (__bf16*)alloc(2*NB);      // hidden-lo, 32 MB
  const size_t LW = 3*(size_t)D_*D_ + 2*(size_t)D_*DFF_;   // elems / layer
  __bf16* wth = (__bf16*)alloc(2*LW*sizeof(__bf16));
  __bf16* wtl = (__bf16*)alloc(2*LW*sizeof(__bf16));
  float*  xout = (float*)d_out;
  // total ws usage ~183 MB

  const size_t OK = 0, OV = (size_t)D_*D_, OO = 2*(size_t)D_*D_;
  const size_t O1 = 3*(size_t)D_*D_, O2 = 3*(size_t)D_*D_ + (size_t)D_*DFF_;

  // weight transposes + splits (recomputed each call; graph-capture safe)
  for (int l = 0; l < L_; ++l) {
    size_t base = (size_t)l * LW;
    transpose_split_kernel<<<dim3(16,16), 256, 0, stream>>>(Wk + (size_t)l*D_*D_,   wth+base+OK, wtl+base+OK, D_,  D_);
    transpose_split_kernel<<<dim3(16,16), 256, 0, stream>>>(Wv + (size_t)l*D_*D_,   wth+base+OV, wtl+base+OV, D_,  D_);
    transpose_split_kernel<<<dim3(16,16), 256, 0, stream>>>(Wo + (size_t)l*D_*D_,   wth+base+OO, wtl+base+OO, D_,  D_);
    transpose_split_kernel<<<dim3(64,16), 256, 0, stream>>>(W1 + (size_t)l*D_*DFF_, wth+base+O1, wtl+base+O1, D_,  DFF_);
    transpose_split_kernel<<<dim3(16,64), 256, 0, stream>>>(W2 + (size_t)l*DFF_*D_, wth+base+O2, wtl+base+O2, DFF_, D_);
  }

  init_x_kernel<<<4096, 256, 0, stream>>>(qe, pos, xh, xl);

  for (int l = 0; l < L_; ++l) {
    size_t base = (size_t)l * LW;
    // q = k = x @ Wk + bk (kq_same), bf16 hi/lo out
    gemm_split3_kernel<<<dim3(4,128), 256, 0, stream>>>(xh, xl, nullptr, nullptr,
        wth+base+OK, wtl+base+OK, bk + (size_t)l*D_, qhb, qlb, BS_, D_, D_, 0);
    // v = (ie + pos) @ Wv + bv  (fused y staging from fp32)
    gemm_split3_kernel<<<dim3(4,128), 256, 0, stream>>>(nullptr, nullptr, ie, pos,
        wth+base+OV, wtl+base+OV, bv + (size_t)l*D_, vhb, vlb, BS_, D_, D_, 4);
    // sparse attention (1-D grid, XCD-affine decode inside)
    attn_kernel<<<dim3(32*H_*B_), 256, 0, stream>>>(qhb, qlb, vhb, vlb, ohb, olb);
    // out-proj -> t (hi/lo; overwrites q region, q is dead)
    gemm_split3_kernel<<<dim3(4,128), 256, 0, stream>>>(ohb, olb, nullptr, nullptr,
        wth+base+OO, wtl+base+OO, bo + (size_t)l*D_, thb, tlb, BS_, D_, D_, 0);
    // x = LN1(x + t)
    resid_ln_kernel<<<BS_/4, 256, 0, stream>>>(xh, xl, thb, tlb,
        ln1g + (size_t)l*D_, ln1b + (size_t)l*D_, xh, xl, nullptr);
    // FFN in two M=8192 chunks (hidden-hi aliases o region, out -> t region)
    for (int ch = 0; ch < 2; ++ch) {
      size_t ao = (size_t)ch*8192*D_;
      gemm_split3_kernel<<<dim3(16,64), 256, 0, stream>>>(xh + ao, xl + ao, nullptr, nullptr,
          wth+base+O1, wtl+base+O1, b1 + (size_t)l*DFF_, hhb, hlb, 8192, DFF_, D_, 1);
      gemm_split3_kernel<<<dim3(4,64), 256, 0, stream>>>(hhb, hlb, nullptr, nullptr,
          wth+base+O2, wtl+base+O2, b2 + (size_t)l*D_, thb + ao, tlb + ao, 8192, D_, DFF_, 0);
    }
    // x = LN2(x + t); final layer writes fp32 straight to d_out
    resid_ln_kernel<<<BS_/4, 256, 0, stream>>>(xh, xl, thb, tlb,
        ln2g + (size_t)l*D_, ln2b + (size_t)l*D_, xh, xl,
        (l == L_-1) ? xout : nullptr);
  }
}